// Round 2
// baseline (312.548 us; speedup 1.0000x reference)
//
#include <hip/hip_runtime.h>
#include <math.h>

#define DIM   2048
#define NEXP  64
#define NGRP  8
#define GSIZE 8
#define TOPK  8
#define TOPKG 4

#define TM   64            // tokens per block
#define TK   32            // K-tile
#define TPB  256
#define NT   (DIM / TK)    // 64 K-tiles

#define NEG_INF (-3.4e38f)

__global__ __launch_bounds__(TPB) void gate_kernel(
    const float* __restrict__ x,
    const float* __restrict__ W,
    const float* __restrict__ b,
    const float* __restrict__ bias,
    float* __restrict__ out_w,
    float* __restrict__ out_i)
{
    // stride TM+4 = 68 floats = 272 B -> 16B-aligned rows, ds_read_b128 OK
    __shared__ float sA[TK][TM + 4];      // x tile, transposed: [k][token]
    __shared__ float sB[TK][NEXP + 4];    // W tile, transposed: [k][expert]
    __shared__ float sS[TM][NEXP + 1];    // score = sigmoid + bias (fp32)
    __shared__ float sWgt[TM][NEXP + 1];  // sigmoid only (fp32)

    const int tid  = threadIdx.x;
    const int tok0 = blockIdx.x * TM;

    const int ty = tid >> 4;          // 0..15 -> 4 tokens
    const int tx = tid & 15;          // 0..15 -> 4 experts

    const int r0 = tid >> 3;          // 0..31
    const int k0 = (tid & 7) * 4;     // 0,4,...,28
    const int r1 = r0 + 32;           // 32..63

    const float* xrow = x + (size_t)tok0 * DIM;

    float4 pa0 = *(const float4*)(xrow + (size_t)r0 * DIM + k0);
    float4 pa1 = *(const float4*)(xrow + (size_t)r1 * DIM + k0);
    float4 pb0 = *(const float4*)(W    + (size_t)r0 * DIM + k0);
    float4 pb1 = *(const float4*)(W    + (size_t)r1 * DIM + k0);

    // fp64 accumulators: products of two fp32 are exact in double; sum error
    // ~1e-15, so computed scores are "true" values. This removes accumulation-
    // order disagreement with the numpy BLAS reference (round-1 failure mode:
    // idx flips at ~1e-6 score gaps from fp32 sequential-sum noise).
    double acc[4][4] = {{0., 0., 0., 0.}, {0., 0., 0., 0.},
                        {0., 0., 0., 0.}, {0., 0., 0., 0.}};

    for (int tile = 0; tile < NT; ++tile) {
        sA[k0 + 0][r0] = pa0.x; sA[k0 + 1][r0] = pa0.y;
        sA[k0 + 2][r0] = pa0.z; sA[k0 + 3][r0] = pa0.w;
        sA[k0 + 0][r1] = pa1.x; sA[k0 + 1][r1] = pa1.y;
        sA[k0 + 2][r1] = pa1.z; sA[k0 + 3][r1] = pa1.w;
        sB[k0 + 0][r0] = pb0.x; sB[k0 + 1][r0] = pb0.y;
        sB[k0 + 2][r0] = pb0.z; sB[k0 + 3][r0] = pb0.w;
        sB[k0 + 0][r1] = pb1.x; sB[k0 + 1][r1] = pb1.y;
        sB[k0 + 2][r1] = pb1.z; sB[k0 + 3][r1] = pb1.w;
        __syncthreads();

        if (tile + 1 < NT) {
            const int kb = (tile + 1) * TK;
            pa0 = *(const float4*)(xrow + (size_t)r0 * DIM + kb + k0);
            pa1 = *(const float4*)(xrow + (size_t)r1 * DIM + kb + k0);
            pb0 = *(const float4*)(W    + (size_t)r0 * DIM + kb + k0);
            pb1 = *(const float4*)(W    + (size_t)r1 * DIM + kb + k0);
        }

#pragma unroll
        for (int kk = 0; kk < TK; ++kk) {
            float4 av = *(const float4*)&sA[kk][ty * 4];
            float4 bv = *(const float4*)&sB[kk][tx * 4];
            double a4[4] = {(double)av.x, (double)av.y, (double)av.z, (double)av.w};
            double b4[4] = {(double)bv.x, (double)bv.y, (double)bv.z, (double)bv.w};
#pragma unroll
            for (int i = 0; i < 4; ++i)
#pragma unroll
                for (int j = 0; j < 4; ++j)
                    acc[i][j] = fma(a4[i], b4[j], acc[i][j]);
        }
        __syncthreads();
    }

    // epilogue: sigmoid in double, round to fp32 BEFORE any comparison so
    // tie semantics match the reference's fp32 score table
    float bvec[4], biasv[4];
#pragma unroll
    for (int j = 0; j < 4; ++j) {
        bvec[j]  = b[tx * 4 + j];
        biasv[j] = bias[tx * 4 + j];
    }
#pragma unroll
    for (int i = 0; i < 4; ++i) {
        const int t = ty * 4 + i;
#pragma unroll
        for (int j = 0; j < 4; ++j) {
            const double logit = acc[i][j] + (double)bvec[j];
            const float wv = (float)(1.0 / (1.0 + exp(-logit)));
            sWgt[t][tx * 4 + j] = wv;
            sS[t][tx * 4 + j]   = wv + biasv[j];   // fp32 add, like reference
        }
    }
    __syncthreads();

    // routing: thread t handles token t (exact reference semantics)
    if (tid < TM) {
        const int t = tid;

        // group scores: sum of top-2 within each group of 8
        float gs[NGRP];
#pragma unroll
        for (int g = 0; g < NGRP; ++g) {
            float m1 = NEG_INF, m2 = NEG_INF;
#pragma unroll
            for (int j = 0; j < GSIZE; ++j) {
                const float v = sS[t][g * GSIZE + j];
                if (v > m1) { m2 = m1; m1 = v; }
                else if (v > m2) { m2 = v; }
            }
            gs[g] = m1 + m2;
        }

        // stable top-4 groups (strict >, ascending scan => lowest index on tie)
        unsigned gmask = 0u;
        for (int r = 0; r < TOPKG; ++r) {
            float best = NEG_INF; int bi = 0;
#pragma unroll
            for (int g = 0; g < NGRP; ++g) {
                const float v = ((gmask >> g) & 1u) ? NEG_INF : gs[g];
                if (v > best) { best = v; bi = g; }
            }
            gmask |= 1u << bi;
        }

        // stable top-8 experts over masked scores (masked groups contribute 0.0,
        // exactly like reference's score_g * mask)
        unsigned long long chosen = 0ull;
        const size_t obase = (size_t)(tok0 + t) * TOPK;
        for (int r = 0; r < TOPK; ++r) {
            float best = NEG_INF; int bi = 0;
            for (int e = 0; e < NEXP; ++e) {
                float v = ((gmask >> (e >> 3)) & 1u) ? sS[t][e] : 0.0f;
                if ((chosen >> e) & 1ull) v = NEG_INF;
                if (v > best) { best = v; bi = e; }
            }
            chosen |= 1ull << (unsigned)bi;
            const float wv = ((gmask >> (bi >> 3)) & 1u) ? sWgt[t][bi] : 0.0f;
            out_w[obase + r] = wv;
            out_i[obase + r] = (float)bi;
        }
    }
}

extern "C" void kernel_launch(void* const* d_in, const int* in_sizes, int n_in,
                              void* d_out, int out_size, void* d_ws, size_t ws_size,
                              hipStream_t stream) {
    const float* x    = (const float*)d_in[0];
    const float* W    = (const float*)d_in[1];
    const float* b    = (const float*)d_in[2];
    const float* bias = (const float*)d_in[3];

    const int n = in_sizes[0] / DIM;      // 16384 tokens
    float* out_w = (float*)d_out;
    float* out_i = out_w + (size_t)n * TOPK;

    gate_kernel<<<dim3(n / TM), dim3(TPB), 0, stream>>>(x, W, b, bias, out_w, out_i);
}